// Round 1
// baseline (2214.203 us; speedup 1.0000x reference)
//
#include <hip/hip_runtime.h>

// ---------------------------------------------------------------------------
// Fused residual-MLP (N=65536, HID=512, NB=20) for gfx950.
//
// Strategy: one persistent workgroup (512 thr = 8 waves) per 64-row tile.
//   - h (residual) lives in registers in MFMA C-layout: h[rb][i][t] is
//     row rb*16 + 4*q + i, col w*64 + 4*c + t   (w=wave, c=lane&15, q=lane>>4)
//   - LN-normalized activations (bf16) round-trip through LDS only.
//   - Weights pre-packed (prep kernel) to bf16 in exact MFMA B-fragment
//     order -> each B fragment is ONE coalesced global_load_dwordx4/wave.
//   - GEMMs: v_mfma_f32_16x16x32_bf16, fp32 accumulate.
// LDS: hn[64][520] bf16 (66560 B) + scr[64][260] f32 (66560 B) + mv (512 B)
//      = 133632 B dynamic (gfx950 allows 160 KiB/WG) -> 1 WG/CU.
// ---------------------------------------------------------------------------

typedef float  fvec4 __attribute__((ext_vector_type(4)));
typedef __bf16 bvec8 __attribute__((ext_vector_type(8)));

#define HN_STRIDE  520   // ushorts per row (sigma=65 odd -> conflict-free b128)
#define SCR_STRIDE 260   // floats per row of scratch
#define SMEM_BYTES (64*HN_STRIDE*2 + 64*SCR_STRIDE*4 + 64*8)

__device__ __forceinline__ unsigned int f2bf(float v) {
    unsigned int u = __float_as_uint(v);
    return (u + 0x7fffu + ((u >> 16) & 1u)) >> 16;   // RNE truncate to bf16
}
__device__ __forceinline__ float silu_f(float v) {
    return v * (1.0f / (1.0f + __expf(-v)));
}

// ---- weight pre-pack: fp32 [b][k][n] -> bf16 MFMA B-fragment stream -------
// frag id f = ((b*2+g)*8 + w)*64 + kc*4 + t ; element j of lane l is
// W[b][ kc*32 + (l>>4)*8 + j ][ w*64 + (l&15)*4 + t ]
__global__ __launch_bounds__(256) void pack_weights(
        const float* __restrict__ w1, const float* __restrict__ w2,
        unsigned short* __restrict__ pk) {
    int tid = blockIdx.x * 256 + threadIdx.x;       // 20*2*8*16*4*64 threads
    int l  = tid & 63;
    int f  = tid >> 6;
    int t  = f & 3;
    int kc = (f >> 2) & 15;
    int w  = (f >> 6) & 7;
    int g  = (f >> 9) & 1;
    int b  = f >> 10;
    const float* src = g ? w2 : w1;
    int k0 = kc * 32 + (l >> 4) * 8;
    int n  = w * 64 + (l & 15) * 4 + t;
    const float* s = src + ((size_t)b * 512 + k0) * 512 + n;
    unsigned int r[4];
#pragma unroll
    for (int j = 0; j < 4; ++j) {
        unsigned int lo = f2bf(s[(size_t)(2*j) * 512]);
        unsigned int hi = f2bf(s[(size_t)(2*j + 1) * 512]);
        r[j] = lo | (hi << 16);
    }
    *(uint4*)(pk + (size_t)tid * 8) = make_uint4(r[0], r[1], r[2], r[3]);
}

// ---- LN stats: per-lane partials -> scr -> 8-thread/row reduce -> mv ------
template <typename GetF>
__device__ __forceinline__ void ln_stats(GetF get, float* scr, float2* mv,
                                         int w, int c, int q, int tid) {
#pragma unroll
    for (int rb = 0; rb < 4; ++rb)
#pragma unroll
        for (int i = 0; i < 4; ++i) {
            float s = 0.f, ss = 0.f;
#pragma unroll
            for (int t = 0; t < 4; ++t) { float v = get(rb, i, t); s += v; ss += v * v; }
            int row = rb * 16 + q * 4 + i;
            *(float2*)(scr + row * SCR_STRIDE + (w * 16 + c) * 2) = make_float2(s, ss);
        }
    __syncthreads();
    {
        int r = tid >> 3, j = tid & 7;
        float s = 0.f, ss = 0.f;
#pragma unroll
        for (int u = 0; u < 16; ++u) {
            float2 p = *(const float2*)(scr + r * SCR_STRIDE + (j * 16 + u) * 2);
            s += p.x; ss += p.y;
        }
        s += __shfl_xor(s, 1); ss += __shfl_xor(ss, 1);
        s += __shfl_xor(s, 2); ss += __shfl_xor(ss, 2);
        s += __shfl_xor(s, 4); ss += __shfl_xor(ss, 4);
        if (j == 0) {
            float mean = s * (1.f / 512.f);
            float var  = ss * (1.f / 512.f) - mean * mean;
            mv[r] = make_float2(mean, rsqrtf(var + 1e-5f));
        }
    }
    __syncthreads();
}

// ---- write normalized bf16 activations to LDS (A operand) -----------------
template <typename GetF>
__device__ __forceinline__ void write_norm(GetF get, unsigned short* hn,
                                           const float2* mv, fvec4 g, fvec4 bv,
                                           int colbase, int q) {
#pragma unroll
    for (int rb = 0; rb < 4; ++rb)
#pragma unroll
        for (int i = 0; i < 4; ++i) {
            int row = rb * 16 + q * 4 + i;
            float2 m = mv[row];
            float v0 = (get(rb, i, 0) - m.x) * m.y * g[0] + bv[0];
            float v1 = (get(rb, i, 1) - m.x) * m.y * g[1] + bv[1];
            float v2 = (get(rb, i, 2) - m.x) * m.y * g[2] + bv[2];
            float v3 = (get(rb, i, 3) - m.x) * m.y * g[3] + bv[3];
            unsigned int lo = f2bf(v0) | (f2bf(v1) << 16);
            unsigned int hi = f2bf(v2) | (f2bf(v3) << 16);
            *(uint2*)(hn + row * HN_STRIDE + colbase) = make_uint2(lo, hi);
        }
    __syncthreads();
}

// ---- one [64,512]x[512,512] GEMM: A from LDS, B streamed from global ------
__device__ __forceinline__ void do_gemm(fvec4 acc[4][4],
                                        const unsigned short* hn,
                                        const unsigned short* __restrict__ wp,
                                        int l, int c, int q) {
#pragma unroll 2
    for (int kc = 0; kc < 16; ++kc) {
        bvec8 a[4], bb[4];
#pragma unroll
        for (int rb = 0; rb < 4; ++rb)
            a[rb] = *(const bvec8*)(hn + (rb * 16 + c) * HN_STRIDE + kc * 32 + q * 8);
#pragma unroll
        for (int t = 0; t < 4; ++t)
            bb[t] = *(const bvec8*)(wp + (size_t)(kc * 4 + t) * 512 + l * 8);
#pragma unroll
        for (int rb = 0; rb < 4; ++rb)
#pragma unroll
            for (int t = 0; t < 4; ++t)
                acc[rb][t] = __builtin_amdgcn_mfma_f32_16x16x32_bf16(
                    a[rb], bb[t], acc[rb][t], 0, 0, 0);
    }
}

__global__ __launch_bounds__(512, 2) void mlp_fused(
        const float* __restrict__ x,
        const float* __restrict__ in_w,  const float* __restrict__ in_b,
        const float* __restrict__ ln1_g, const float* __restrict__ ln1_b,
        const float* __restrict__ fc1_b,
        const float* __restrict__ ln2_g, const float* __restrict__ ln2_b,
        const float* __restrict__ fc2_b,
        const float* __restrict__ out_ln_g, const float* __restrict__ out_ln_b,
        const float* __restrict__ out_w, const float* __restrict__ out_b,
        const unsigned short* __restrict__ wpk,
        float* __restrict__ out) {
    extern __shared__ char smem[];
    unsigned short* hn = (unsigned short*)smem;                  // 66560 B
    float* scr = (float*)(smem + 64 * HN_STRIDE * 2);            // 66560 B
    float2* mv = (float2*)(smem + 64 * HN_STRIDE * 2 + 64 * SCR_STRIDE * 4);

    const int tid = threadIdx.x;
    const int w = tid >> 6, l = tid & 63, c = l & 15, q = l >> 4;
    const int colbase = w * 64 + c * 4;
    const int row0 = blockIdx.x * 64;

    float h[4][4][4];   // [rb][i][t]

    // ---- in-proj + SiLU ----
    {
        fvec4 iw0 = *(const fvec4*)(in_w + colbase);
        fvec4 iw1 = *(const fvec4*)(in_w + 512 + colbase);
        fvec4 ib  = *(const fvec4*)(in_b + colbase);
#pragma unroll
        for (int rb = 0; rb < 4; ++rb)
#pragma unroll
            for (int i = 0; i < 4; ++i) {
                int row = rb * 16 + q * 4 + i;
                float2 xv = *(const float2*)(x + (size_t)(row0 + row) * 2);
#pragma unroll
                for (int t = 0; t < 4; ++t)
                    h[rb][i][t] = silu_f(xv.x * iw0[t] + xv.y * iw1[t] + ib[t]);
            }
    }

    const size_t wchunk = 16 * 4 * 64 * 8;   // 32768 ushorts per (b,g,w)
    auto getH = [&](int rb, int i, int t) { return h[rb][i][t]; };

    for (int b = 0; b < 20; ++b) {
        fvec4 g1 = *(const fvec4*)(ln1_g + b * 512 + colbase);
        fvec4 b1 = *(const fvec4*)(ln1_b + b * 512 + colbase);
        fvec4 c1 = *(const fvec4*)(fc1_b + b * 512 + colbase);
        fvec4 g2 = *(const fvec4*)(ln2_g + b * 512 + colbase);
        fvec4 b2 = *(const fvec4*)(ln2_b + b * 512 + colbase);
        fvec4 c2 = *(const fvec4*)(fc2_b + b * 512 + colbase);

        // LN1 -> hn
        ln_stats(getH, scr, mv, w, c, q, tid);
        write_norm(getH, hn, mv, g1, b1, colbase, q);

        // GEMM1
        fvec4 acc[4][4];
#pragma unroll
        for (int rb = 0; rb < 4; ++rb)
#pragma unroll
            for (int t = 0; t < 4; ++t) acc[rb][t] = (fvec4){0.f, 0.f, 0.f, 0.f};
        do_gemm(acc, hn, wpk + ((size_t)(b * 2 + 0) * 8 + w) * wchunk, l, c, q);

        // bias + SiLU
#pragma unroll
        for (int rb = 0; rb < 4; ++rb)
#pragma unroll
            for (int t = 0; t < 4; ++t)
#pragma unroll
                for (int i = 0; i < 4; ++i)
                    acc[rb][t][i] = silu_f(acc[rb][t][i] + c1[t]);

        // LN2 -> tn (reuses hn buffer; ln_stats barrier guarantees GEMM1 done)
        auto getA = [&](int rb, int i, int t) { return acc[rb][t][i]; };
        ln_stats(getA, scr, mv, w, c, q, tid);
        write_norm(getA, hn, mv, g2, b2, colbase, q);

        // GEMM2
#pragma unroll
        for (int rb = 0; rb < 4; ++rb)
#pragma unroll
            for (int t = 0; t < 4; ++t) acc[rb][t] = (fvec4){0.f, 0.f, 0.f, 0.f};
        do_gemm(acc, hn, wpk + ((size_t)(b * 2 + 1) * 8 + w) * wchunk, l, c, q);

        // residual
#pragma unroll
        for (int rb = 0; rb < 4; ++rb)
#pragma unroll
            for (int i = 0; i < 4; ++i)
#pragma unroll
                for (int t = 0; t < 4; ++t)
                    h[rb][i][t] += acc[rb][t][i] + c2[t];
    }

    // ---- final LN + SiLU + out-proj ----
    ln_stats(getH, scr, mv, w, c, q, tid);
    {
        fvec4 og = *(const fvec4*)(out_ln_g + colbase);
        fvec4 ob = *(const fvec4*)(out_ln_b + colbase);
        fvec4 ow = *(const fvec4*)(out_w + colbase);
#pragma unroll
        for (int rb = 0; rb < 4; ++rb)
#pragma unroll
            for (int i = 0; i < 4; ++i) {
                int row = rb * 16 + q * 4 + i;
                float2 m = mv[row];
                float p = 0.f;
#pragma unroll
                for (int t = 0; t < 4; ++t) {
                    float v = (h[rb][i][t] - m.x) * m.y * og[t] + ob[t];
                    p += silu_f(v) * ow[t];
                }
                scr[row * SCR_STRIDE + (w * 16 + c) * 2] = p;
            }
    }
    __syncthreads();
    {
        int r = tid >> 3, j = tid & 7;
        float s = 0.f;
#pragma unroll
        for (int u = 0; u < 16; ++u)
            s += scr[r * SCR_STRIDE + (j * 16 + u) * 2];
        s += __shfl_xor(s, 1);
        s += __shfl_xor(s, 2);
        s += __shfl_xor(s, 4);
        if (j == 0) out[row0 + r] = s + out_b[0];
    }
}

extern "C" void kernel_launch(void* const* d_in, const int* in_sizes, int n_in,
                              void* d_out, int out_size, void* d_ws, size_t ws_size,
                              hipStream_t stream) {
    const float* x        = (const float*)d_in[0];
    const float* in_w     = (const float*)d_in[1];
    const float* in_b     = (const float*)d_in[2];
    const float* ln1_g    = (const float*)d_in[3];
    const float* ln1_b    = (const float*)d_in[4];
    const float* fc1_w    = (const float*)d_in[5];
    const float* fc1_b    = (const float*)d_in[6];
    const float* ln2_g    = (const float*)d_in[7];
    const float* ln2_b    = (const float*)d_in[8];
    const float* fc2_w    = (const float*)d_in[9];
    const float* fc2_b    = (const float*)d_in[10];
    const float* out_ln_g = (const float*)d_in[11];
    const float* out_ln_b = (const float*)d_in[12];
    const float* out_w    = (const float*)d_in[13];
    const float* out_b    = (const float*)d_in[14];
    float* out = (float*)d_out;
    unsigned short* wpk = (unsigned short*)d_ws;   // needs 20,971,520 B

    (void)hipFuncSetAttribute((const void*)mlp_fused,
                              hipFuncAttributeMaxDynamicSharedMemorySize, SMEM_BYTES);

    // 20*2*8*16*4 frags * 64 lanes = 1,310,720 threads
    pack_weights<<<5120, 256, 0, stream>>>(fc1_w, fc2_w, wpk);
    mlp_fused<<<1024, 512, SMEM_BYTES, stream>>>(
        x, in_w, in_b, ln1_g, ln1_b, fc1_b, ln2_g, ln2_b, fc2_b,
        out_ln_g, out_ln_b, out_w, out_b, wpk, out);
}

// Round 4
// 2130.940 us; speedup vs baseline: 1.0391x; 1.0391x over previous
//
#include <hip/hip_runtime.h>

// ---------------------------------------------------------------------------
// Fused residual-MLP (N=65536, HID=512, NB=20) for gfx950.  Round 4.
//
// 32-row tiles, 2048 WGs (512 thr = 8 waves, each wave 32 rows x 64 cols).
// Per-lane state: h[2][4][4]=32 + acc[2][4]=32 + frags ~24 + addr => ~115
// regs -> fits 128-reg cap (launch_bounds 512,4) WITHOUT spills => 2 WG/CU.
// This buys cross-WG overlap of LN(VALU) phases with GEMM(MFMA) phases,
// which R1's single-WG barrier lockstep serialized (960us VALU + 660us MFMA
// = 2.4ms observed).
//
// Primitives are R1-exact (the only passing kernel): full per-lane partial
// writes in ln_stats (NO in-wave pre-reduction - suspect in R2/R3 failures),
// R1's write_norm arithmetic form, R1's hn layout + do_gemm.
// scr is transposed to [partial][row] stride-33 f32 planes: fixes R1's 8-way
// phase-2 read conflict (now <=4-way).
// LDS: hn 32*520*2=33280 + 2 planes 128*33*4=33792 + mv 256 = 67328 B.
// ---------------------------------------------------------------------------

typedef float  fvec4 __attribute__((ext_vector_type(4)));
typedef __bf16 bvec8 __attribute__((ext_vector_type(8)));

#define HN_STRIDE  520                    // ushorts per row (R1-proven)
#define PLANE      (128 * 33)             // floats per scr plane
#define SMEM_BYTES (32*HN_STRIDE*2 + 2*PLANE*4 + 32*8)   // 67328 B

__device__ __forceinline__ unsigned int f2bf(float v) {
    unsigned int u = __float_as_uint(v);
    return (u + 0x7fffu + ((u >> 16) & 1u)) >> 16;   // RNE to bf16
}
__device__ __forceinline__ float silu_f(float v) {
    return v * (1.0f / (1.0f + __expf(-v)));
}

// ---- weight pre-pack: fp32 [b][k][n] -> bf16 MFMA B-fragment stream -------
// (unchanged from R1 - layout depends only on weights)
__global__ __launch_bounds__(256) void pack_weights(
        const float* __restrict__ w1, const float* __restrict__ w2,
        unsigned short* __restrict__ pk) {
    int tid = blockIdx.x * 256 + threadIdx.x;
    int l  = tid & 63;
    int f  = tid >> 6;
    int t  = f & 3;
    int kc = (f >> 2) & 15;
    int w  = (f >> 6) & 7;
    int g  = (f >> 9) & 1;
    int b  = f >> 10;
    const float* src = g ? w2 : w1;
    int k0 = kc * 32 + (l >> 4) * 8;
    int n  = w * 64 + (l & 15) * 4 + t;
    const float* s = src + ((size_t)b * 512 + k0) * 512 + n;
    unsigned int r[4];
#pragma unroll
    for (int j = 0; j < 4; ++j) {
        unsigned int lo = f2bf(s[(size_t)(2*j) * 512]);
        unsigned int hi = f2bf(s[(size_t)(2*j + 1) * 512]);
        r[j] = lo | (hi << 16);
    }
    *(uint4*)(pk + (size_t)tid * 8) = make_uint4(r[0], r[1], r[2], r[3]);
}

// ---- LN stats (R1 style: every lane writes its raw partial) ---------------
// plane_s / plane_ss: [partial 0..127][row 0..31], stride 33.
// partial index of lane = 16*w + c. Phase 2: 256 threads, r=tid>>3, j=tid&7,
// sum p = 16j+u over u=0..15, then shfl_xor(1,2,4) over j, j==0 writes mv.
template <typename GetF>
__device__ __forceinline__ void ln_stats(GetF get, float* plane_s,
                                         float* plane_ss, float2* mv,
                                         int w, int c, int q, int tid) {
    const int pcol = 16 * w + c;
#pragma unroll
    for (int rb = 0; rb < 2; ++rb)
#pragma unroll
        for (int i = 0; i < 4; ++i) {
            float s = 0.f, ss = 0.f;
#pragma unroll
            for (int t = 0; t < 4; ++t) { float v = get(rb, i, t); s += v; ss += v * v; }
            int row = rb * 16 + q * 4 + i;
            plane_s [pcol * 33 + row] = s;
            plane_ss[pcol * 33 + row] = ss;
        }
    __syncthreads();
    if (tid < 256) {
        int r = tid >> 3, j = tid & 7;
        float s = 0.f, ss = 0.f;
#pragma unroll
        for (int u = 0; u < 16; ++u) {
            s  += plane_s [(j * 16 + u) * 33 + r];
            ss += plane_ss[(j * 16 + u) * 33 + r];
        }
        s += __shfl_xor(s, 1); ss += __shfl_xor(ss, 1);
        s += __shfl_xor(s, 2); ss += __shfl_xor(ss, 2);
        s += __shfl_xor(s, 4); ss += __shfl_xor(ss, 4);
        if (j == 0) {
            float mean = s * (1.f / 512.f);
            float var  = ss * (1.f / 512.f) - mean * mean;
            mv[r] = make_float2(mean, rsqrtf(var + 1e-5f));
        }
    }
    __syncthreads();
}

// ---- write normalized bf16 activations to hn (R1-exact arithmetic) --------
template <typename GetF>
__device__ __forceinline__ void write_norm(GetF get, unsigned short* hn,
                                           const float2* mv, fvec4 g, fvec4 bv,
                                           int colbase, int q) {
#pragma unroll
    for (int rb = 0; rb < 2; ++rb)
#pragma unroll
        for (int i = 0; i < 4; ++i) {
            int row = rb * 16 + q * 4 + i;
            float2 m = mv[row];
            float v0 = (get(rb, i, 0) - m.x) * m.y * g[0] + bv[0];
            float v1 = (get(rb, i, 1) - m.x) * m.y * g[1] + bv[1];
            float v2 = (get(rb, i, 2) - m.x) * m.y * g[2] + bv[2];
            float v3 = (get(rb, i, 3) - m.x) * m.y * g[3] + bv[3];
            unsigned int lo = f2bf(v0) | (f2bf(v1) << 16);
            unsigned int hi = f2bf(v2) | (f2bf(v3) << 16);
            *(uint2*)(hn + row * HN_STRIDE + colbase) = make_uint2(lo, hi);
        }
    __syncthreads();
}

// ---- one [32,512]x[512,512] GEMM: A from LDS, B streamed from global ------
__device__ __forceinline__ void do_gemm(fvec4 acc[2][4],
                                        const unsigned short* hn,
                                        const unsigned short* __restrict__ wp,
                                        int l, int c, int q) {
#pragma unroll 2
    for (int kc = 0; kc < 16; ++kc) {
        bvec8 a[2], bb[4];
#pragma unroll
        for (int rb = 0; rb < 2; ++rb)
            a[rb] = *(const bvec8*)(hn + (rb * 16 + c) * HN_STRIDE + kc * 32 + q * 8);
#pragma unroll
        for (int t = 0; t < 4; ++t)
            bb[t] = *(const bvec8*)(wp + (size_t)(kc * 4 + t) * 512 + l * 8);
#pragma unroll
        for (int rb = 0; rb < 2; ++rb)
#pragma unroll
            for (int t = 0; t < 4; ++t)
                acc[rb][t] = __builtin_amdgcn_mfma_f32_16x16x32_bf16(
                    a[rb], bb[t], acc[rb][t], 0, 0, 0);
    }
}

__global__ __launch_bounds__(512, 4) void mlp_fused(
        const float* __restrict__ x,
        const float* __restrict__ in_w,  const float* __restrict__ in_b,
        const float* __restrict__ ln1_g, const float* __restrict__ ln1_b,
        const float* __restrict__ fc1_b,
        const float* __restrict__ ln2_g, const float* __restrict__ ln2_b,
        const float* __restrict__ fc2_b,
        const float* __restrict__ out_ln_g, const float* __restrict__ out_ln_b,
        const float* __restrict__ out_w, const float* __restrict__ out_b,
        const unsigned short* __restrict__ wpk,
        float* __restrict__ out) {
    extern __shared__ char smem[];
    unsigned short* hn = (unsigned short*)smem;                  // 33280 B
    float* plane_s  = (float*)(smem + 32 * HN_STRIDE * 2);       // 16896 B
    float* plane_ss = plane_s + PLANE;                           // 16896 B
    float2* mv = (float2*)(smem + 32 * HN_STRIDE * 2 + 2 * PLANE * 4); // 256 B

    const int tid = threadIdx.x;
    const int w = tid >> 6, l = tid & 63, c = l & 15, q = l >> 4;
    const int colbase = w * 64 + c * 4;
    const int row0 = blockIdx.x * 32;

    float h[2][4][4];   // [rb][i][t]

    // ---- in-proj + SiLU ----
    {
        fvec4 iw0 = *(const fvec4*)(in_w + colbase);
        fvec4 iw1 = *(const fvec4*)(in_w + 512 + colbase);
        fvec4 ib  = *(const fvec4*)(in_b + colbase);
#pragma unroll
        for (int rb = 0; rb < 2; ++rb)
#pragma unroll
            for (int i = 0; i < 4; ++i) {
                int row = rb * 16 + q * 4 + i;
                float2 xv = *(const float2*)(x + (size_t)(row0 + row) * 2);
#pragma unroll
                for (int t = 0; t < 4; ++t)
                    h[rb][i][t] = silu_f(xv.x * iw0[t] + xv.y * iw1[t] + ib[t]);
            }
    }

    const size_t wchunk = 16 * 4 * 64 * 8;   // 32768 ushorts per (b,g,w)
    auto getH = [&](int rb, int i, int t) { return h[rb][i][t]; };

    for (int b = 0; b < 20; ++b) {
        fvec4 g1 = *(const fvec4*)(ln1_g + b * 512 + colbase);
        fvec4 b1 = *(const fvec4*)(ln1_b + b * 512 + colbase);
        fvec4 c1 = *(const fvec4*)(fc1_b + b * 512 + colbase);
        fvec4 g2 = *(const fvec4*)(ln2_g + b * 512 + colbase);
        fvec4 b2 = *(const fvec4*)(ln2_b + b * 512 + colbase);
        fvec4 c2 = *(const fvec4*)(fc2_b + b * 512 + colbase);

        // LN1 -> hn
        ln_stats(getH, plane_s, plane_ss, mv, w, c, q, tid);
        write_norm(getH, hn, mv, g1, b1, colbase, q);

        // GEMM1
        fvec4 acc[2][4];
#pragma unroll
        for (int rb = 0; rb < 2; ++rb)
#pragma unroll
            for (int t = 0; t < 4; ++t) acc[rb][t] = (fvec4){0.f, 0.f, 0.f, 0.f};
        do_gemm(acc, hn, wpk + ((size_t)(b * 2 + 0) * 8 + w) * wchunk, l, c, q);

        // bias + SiLU
#pragma unroll
        for (int rb = 0; rb < 2; ++rb)
#pragma unroll
            for (int t = 0; t < 4; ++t)
#pragma unroll
                for (int i = 0; i < 4; ++i)
                    acc[rb][t][i] = silu_f(acc[rb][t][i] + c1[t]);

        // LN2 -> hn (ln_stats' first barrier guarantees GEMM1 hn reads done)
        auto getA = [&](int rb, int i, int t) { return acc[rb][t][i]; };
        ln_stats(getA, plane_s, plane_ss, mv, w, c, q, tid);
        write_norm(getA, hn, mv, g2, b2, colbase, q);

        // GEMM2
#pragma unroll
        for (int rb = 0; rb < 2; ++rb)
#pragma unroll
            for (int t = 0; t < 4; ++t) acc[rb][t] = (fvec4){0.f, 0.f, 0.f, 0.f};
        do_gemm(acc, hn, wpk + ((size_t)(b * 2 + 1) * 8 + w) * wchunk, l, c, q);

        // residual
#pragma unroll
        for (int rb = 0; rb < 2; ++rb)
#pragma unroll
            for (int i = 0; i < 4; ++i)
#pragma unroll
                for (int t = 0; t < 4; ++t)
                    h[rb][i][t] += acc[rb][t][i] + c2[t];
    }

    // ---- final LN + SiLU + out-proj ----
    ln_stats(getH, plane_s, plane_ss, mv, w, c, q, tid);
    {
        fvec4 og = *(const fvec4*)(out_ln_g + colbase);
        fvec4 ob = *(const fvec4*)(out_ln_b + colbase);
        fvec4 ow = *(const fvec4*)(out_w + colbase);
        const int pcol = 16 * w + c;
#pragma unroll
        for (int rb = 0; rb < 2; ++rb)
#pragma unroll
            for (int i = 0; i < 4; ++i) {
                int row = rb * 16 + q * 4 + i;
                float2 m = mv[row];
                float p = 0.f;
#pragma unroll
                for (int t = 0; t < 4; ++t) {
                    float v = (h[rb][i][t] - m.x) * m.y * og[t] + ob[t];
                    p += silu_f(v) * ow[t];
                }
                plane_s[pcol * 33 + row] = p;
            }
    }
    __syncthreads();
    if (tid < 256) {
        int r = tid >> 3, j = tid & 7;
        float s = 0.f;
#pragma unroll
        for (int u = 0; u < 16; ++u)
            s += plane_s[(j * 16 + u) * 33 + r];
        s += __shfl_xor(s, 1);
        s += __shfl_xor(s, 2);
        s += __shfl_xor(s, 4);
        if (j == 0) out[row0 + r] = s + out_b[0];
    }
}

extern "C" void kernel_launch(void* const* d_in, const int* in_sizes, int n_in,
                              void* d_out, int out_size, void* d_ws, size_t ws_size,
                              hipStream_t stream) {
    const float* x        = (const float*)d_in[0];
    const float* in_w     = (const float*)d_in[1];
    const float* in_b     = (const float*)d_in[2];
    const float* ln1_g    = (const float*)d_in[3];
    const float* ln1_b    = (const float*)d_in[4];
    const float* fc1_w    = (const float*)d_in[5];
    const float* fc1_b    = (const float*)d_in[6];
    const float* ln2_g    = (const float*)d_in[7];
    const float* ln2_b    = (const float*)d_in[8];
    const float* fc2_w    = (const float*)d_in[9];
    const float* fc2_b    = (const float*)d_in[10];
    const float* out_ln_g = (const float*)d_in[11];
    const float* out_ln_b = (const float*)d_in[12];
    const float* out_w    = (const float*)d_in[13];
    const float* out_b    = (const float*)d_in[14];
    float* out = (float*)d_out;
    unsigned short* wpk = (unsigned short*)d_ws;   // needs 20,971,520 B

    (void)hipFuncSetAttribute((const void*)mlp_fused,
                              hipFuncAttributeMaxDynamicSharedMemorySize, SMEM_BYTES);

    pack_weights<<<5120, 256, 0, stream>>>(fc1_w, fc2_w, wpk);
    mlp_fused<<<2048, 512, SMEM_BYTES, stream>>>(
        x, in_w, in_b, ln1_g, ln1_b, fc1_b, ln2_g, ln2_b, fc2_b,
        out_ln_g, out_ln_b, out_w, out_b, wpk, out);
}

// Round 5
// 2078.342 us; speedup vs baseline: 1.0654x; 1.0253x over previous
//
#include <hip/hip_runtime.h>

// ---------------------------------------------------------------------------
// Fused residual-MLP (N=65536, HID=512, NB=20) for gfx950.  Round 5.
//
// R4 post-mortem: L2-BW-bound on the weight stream (42 GB @ 17.5 TB/s).
// Weight traffic = (N / rows_per_WG) * 20.5 MB  ->  bigger row tile wins.
//
// R5: 64-row tiles, 1024 WGs x 1024 threads (16 waves). Wave w owns a
// DISTINCT 32-col slice (no intra-WG B redundancy): per GEMM each WG reads
// the 512 KB weight matrix exactly once -> 21 GB total (half of R4).
// Per-lane: h[4][4][2]=32 + acc[4][2]x4=32 (AGPR) + frags -> ~122 regs,
// fits the 128 cap of __launch_bounds__(1024,4) with NO spills (R2/R3's
// failures were both in the deep-spill regime; R4's no-spill build passed).
// GEMM2 trick: acc initialized to h + c2 -> residual add free, h dead
// during GEMM2.
// LN partials: per-lane 2-col (s,ss) packed as 2xbf16 in one u32 plane
// [pcol=16w+c][row], stride 67 (bank-audited <=2-way). Error ~2e-4.
// LDS: hn 64*520*2=66560 + plane 256*67*4=68608 + mv 512 = 135680 B
//   -> 1 WG/CU, 16 waves/CU.
// ---------------------------------------------------------------------------

typedef float  fvec4 __attribute__((ext_vector_type(4)));
typedef __bf16 bvec8 __attribute__((ext_vector_type(8)));

#define HN_STRIDE 520                 // ushorts per hn row (R1/R4-proven)
#define PL_STRIDE 67                  // u32 per pcol (67c mod 32 = 3c -> <=2-way)
#define N_PCOL    256
#define WCHUNK    16384               // ushorts per (b,g,w) weight chunk
#define SMEM_BYTES (64*HN_STRIDE*2 + N_PCOL*PL_STRIDE*4 + 64*8)  // 135680

__device__ __forceinline__ unsigned int f2bf(float v) {
    unsigned int u = __float_as_uint(v);
    return (u + 0x7fffu + ((u >> 16) & 1u)) >> 16;   // RNE to bf16
}
__device__ __forceinline__ float silu_f(float v) {
    return v * (1.0f / (1.0f + __expf(-v)));
}

// ---- weight pre-pack: fp32 [b][k][n] -> bf16 MFMA B-fragment stream -------
// frag f = ((b*2+g)*16 + w)*32 + kc*2 + t ; lane l elem j holds
// W[b][ kc*32 + (l>>4)*8 + j ][ w*32 + (l&15)*2 + t ]
__global__ __launch_bounds__(256) void pack_weights(
        const float* __restrict__ w1, const float* __restrict__ w2,
        unsigned short* __restrict__ pk) {
    int tid = blockIdx.x * 256 + threadIdx.x;   // 20480 frags * 64 lanes
    int l  = tid & 63;
    int f  = tid >> 6;
    int t  = f & 1;
    int kc = (f >> 1) & 15;
    int w  = (f >> 5) & 15;
    int g  = (f >> 9) & 1;
    int b  = f >> 10;
    const float* src = g ? w2 : w1;
    int k0 = kc * 32 + (l >> 4) * 8;
    int n  = w * 32 + (l & 15) * 2 + t;
    const float* s = src + ((size_t)b * 512 + k0) * 512 + n;
    unsigned int r[4];
#pragma unroll
    for (int j = 0; j < 4; ++j) {
        unsigned int lo = f2bf(s[(size_t)(2*j) * 512]);
        unsigned int hi = f2bf(s[(size_t)(2*j + 1) * 512]);
        r[j] = lo | (hi << 16);
    }
    *(uint4*)(pk + (size_t)tid * 8) = make_uint4(r[0], r[1], r[2], r[3]);
}

// ---- LN stats: every lane writes its 2-col partial (packed bf16) ----------
template <typename GetF>
__device__ __forceinline__ void ln_stats(GetF get, unsigned int* plane,
                                         float2* mv, int pcol, int q, int tid) {
#pragma unroll
    for (int rb = 0; rb < 4; ++rb)
#pragma unroll
        for (int i = 0; i < 4; ++i) {
            float v0 = get(rb, i, 0), v1 = get(rb, i, 1);
            float s  = v0 + v1;
            float ss = v0 * v0 + v1 * v1;
            int row = rb * 16 + q * 4 + i;
            plane[pcol * PL_STRIDE + row] = f2bf(s) | (f2bf(ss) << 16);
        }
    __syncthreads();
    if (tid < 512) {
        int r = tid >> 3, j = tid & 7;
        float s = 0.f, ss = 0.f;
#pragma unroll
        for (int u = 0; u < 32; ++u) {
            unsigned int pv = plane[(j + 8 * u) * PL_STRIDE + r];
            s  += __uint_as_float(pv << 16);
            ss += __uint_as_float(pv & 0xFFFF0000u);
        }
        s += __shfl_xor(s, 1); ss += __shfl_xor(ss, 1);
        s += __shfl_xor(s, 2); ss += __shfl_xor(ss, 2);
        s += __shfl_xor(s, 4); ss += __shfl_xor(ss, 4);
        if (j == 0) {
            float mean = s * (1.f / 512.f);
            float var  = ss * (1.f / 512.f) - mean * mean;
            mv[r] = make_float2(mean, rsqrtf(var + 1e-5f));
        }
    }
    __syncthreads();
}

// ---- write normalized bf16 activations to hn (R1-exact arithmetic) --------
template <typename GetF>
__device__ __forceinline__ void write_norm(GetF get, unsigned short* hn,
                                           const float2* mv, float2 g, float2 bv,
                                           int colbase, int q) {
#pragma unroll
    for (int rb = 0; rb < 4; ++rb)
#pragma unroll
        for (int i = 0; i < 4; ++i) {
            int row = rb * 16 + q * 4 + i;
            float2 m = mv[row];
            float v0 = (get(rb, i, 0) - m.x) * m.y * g.x + bv.x;
            float v1 = (get(rb, i, 1) - m.x) * m.y * g.y + bv.y;
            *(unsigned int*)(hn + row * HN_STRIDE + colbase) =
                f2bf(v0) | (f2bf(v1) << 16);
        }
    __syncthreads();
}

// ---- one [64,512]x[512,512] GEMM: A from LDS, B streamed from global ------
__device__ __forceinline__ void do_gemm(fvec4 acc[4][2],
                                        const unsigned short* hn,
                                        const unsigned short* __restrict__ wp,
                                        int l, int c, int q) {
#pragma unroll 2
    for (int kc = 0; kc < 16; ++kc) {
        bvec8 a[4], bb[2];
#pragma unroll
        for (int rb = 0; rb < 4; ++rb)
            a[rb] = *(const bvec8*)(hn + (rb * 16 + c) * HN_STRIDE + kc * 32 + q * 8);
#pragma unroll
        for (int t = 0; t < 2; ++t)
            bb[t] = *(const bvec8*)(wp + (kc * 2 + t) * 512 + l * 8);
#pragma unroll
        for (int rb = 0; rb < 4; ++rb)
#pragma unroll
            for (int t = 0; t < 2; ++t)
                acc[rb][t] = __builtin_amdgcn_mfma_f32_16x16x32_bf16(
                    a[rb], bb[t], acc[rb][t], 0, 0, 0);
    }
}

__global__ __launch_bounds__(1024, 4) void mlp_fused(
        const float* __restrict__ x,
        const float* __restrict__ in_w,  const float* __restrict__ in_b,
        const float* __restrict__ ln1_g, const float* __restrict__ ln1_b,
        const float* __restrict__ fc1_b,
        const float* __restrict__ ln2_g, const float* __restrict__ ln2_b,
        const float* __restrict__ fc2_b,
        const float* __restrict__ out_ln_g, const float* __restrict__ out_ln_b,
        const float* __restrict__ out_w, const float* __restrict__ out_b,
        const unsigned short* __restrict__ wpk,
        float* __restrict__ out) {
    extern __shared__ char smem[];
    unsigned short* hn = (unsigned short*)smem;                      // 66560 B
    unsigned int* plane = (unsigned int*)(smem + 64 * HN_STRIDE * 2);// 68608 B
    float* planef = (float*)plane;
    float2* mv = (float2*)(smem + 64 * HN_STRIDE * 2 + N_PCOL * PL_STRIDE * 4);

    const int tid = threadIdx.x;
    const int w = tid >> 6;            // wave 0..15 -> cols [32w, 32w+32)
    const int l = tid & 63, c = l & 15, q = l >> 4;
    const int colbase = w * 32 + c * 2;
    const int pcol = w * 16 + c;       // 0..255
    const int row0 = blockIdx.x * 64;

    float h[4][4][2];   // [rb][i][t] : row rb*16+q*4+i, col colbase+t

    // ---- in-proj + SiLU ----
    {
        float2 iw0 = *(const float2*)(in_w + colbase);
        float2 iw1 = *(const float2*)(in_w + 512 + colbase);
        float2 ib  = *(const float2*)(in_b + colbase);
#pragma unroll
        for (int rb = 0; rb < 4; ++rb)
#pragma unroll
            for (int i = 0; i < 4; ++i) {
                int row = rb * 16 + q * 4 + i;
                float2 xv = *(const float2*)(x + (size_t)(row0 + row) * 2);
                h[rb][i][0] = silu_f(xv.x * iw0.x + xv.y * iw1.x + ib.x);
                h[rb][i][1] = silu_f(xv.x * iw0.y + xv.y * iw1.y + ib.y);
            }
    }

    auto getH = [&](int rb, int i, int t) { return h[rb][i][t]; };

    for (int b = 0; b < 20; ++b) {
        float2 g1 = *(const float2*)(ln1_g + b * 512 + colbase);
        float2 b1 = *(const float2*)(ln1_b + b * 512 + colbase);
        float2 c1 = *(const float2*)(fc1_b + b * 512 + colbase);
        float2 g2 = *(const float2*)(ln2_g + b * 512 + colbase);
        float2 b2 = *(const float2*)(ln2_b + b * 512 + colbase);
        float2 c2 = *(const float2*)(fc2_b + b * 512 + colbase);
        float c1v[2] = {c1.x, c1.y};
        float c2v[2] = {c2.x, c2.y};

        // LN1 -> hn
        ln_stats(getH, plane, mv, pcol, q, tid);
        write_norm(getH, hn, mv, g1, b1, colbase, q);

        // GEMM1: acc = LN1(h) @ W1
        fvec4 acc[4][2];
#pragma unroll
        for (int rb = 0; rb < 4; ++rb)
#pragma unroll
            for (int t = 0; t < 2; ++t) acc[rb][t] = (fvec4){0.f, 0.f, 0.f, 0.f};
        do_gemm(acc, hn, wpk + ((size_t)(b * 2 + 0) * 16 + w) * WCHUNK, l, c, q);

        // bias + SiLU
#pragma unroll
        for (int rb = 0; rb < 4; ++rb)
#pragma unroll
            for (int t = 0; t < 2; ++t)
#pragma unroll
                for (int i = 0; i < 4; ++i)
                    acc[rb][t][i] = silu_f(acc[rb][t][i] + c1v[t]);

        // LN2 -> hn (ln_stats' first barrier covers GEMM1's hn reads)
        auto getA = [&](int rb, int i, int t) { return acc[rb][t][i]; };
        ln_stats(getA, plane, mv, pcol, q, tid);
        write_norm(getA, hn, mv, g2, b2, colbase, q);

        // GEMM2: acc = h + c2 (residual+bias pre-folded), accumulate t@W2
#pragma unroll
        for (int rb = 0; rb < 4; ++rb)
#pragma unroll
            for (int t = 0; t < 2; ++t)
#pragma unroll
                for (int i = 0; i < 4; ++i)
                    acc[rb][t][i] = h[rb][i][t] + c2v[t];
        do_gemm(acc, hn, wpk + ((size_t)(b * 2 + 1) * 16 + w) * WCHUNK, l, c, q);

        // new residual
#pragma unroll
        for (int rb = 0; rb < 4; ++rb)
#pragma unroll
            for (int i = 0; i < 4; ++i)
#pragma unroll
                for (int t = 0; t < 2; ++t)
                    h[rb][i][t] = acc[rb][t][i];
    }

    // ---- final LN + SiLU + out-proj ----
    ln_stats(getH, plane, mv, pcol, q, tid);
    {
        float2 og = *(const float2*)(out_ln_g + colbase);
        float2 ob = *(const float2*)(out_ln_b + colbase);
        float2 ow = *(const float2*)(out_w + colbase);
#pragma unroll
        for (int rb = 0; rb < 4; ++rb)
#pragma unroll
            for (int i = 0; i < 4; ++i) {
                int row = rb * 16 + q * 4 + i;
                float2 m = mv[row];
                float v0 = (h[rb][i][0] - m.x) * m.y * og.x + ob.x;
                float v1 = (h[rb][i][1] - m.x) * m.y * og.y + ob.y;
                float p = silu_f(v0) * ow.x + silu_f(v1) * ow.y;
                planef[pcol * PL_STRIDE + row] = p;
            }
    }
    __syncthreads();
    if (tid < 512) {
        int r = tid >> 3, j = tid & 7;
        float s = 0.f;
#pragma unroll
        for (int u = 0; u < 32; ++u)
            s += planef[(j + 8 * u) * PL_STRIDE + r];
        s += __shfl_xor(s, 1);
        s += __shfl_xor(s, 2);
        s += __shfl_xor(s, 4);
        if (j == 0) out[row0 + r] = s + out_b[0];
    }
}

extern "C" void kernel_launch(void* const* d_in, const int* in_sizes, int n_in,
                              void* d_out, int out_size, void* d_ws, size_t ws_size,
                              hipStream_t stream) {
    const float* x        = (const float*)d_in[0];
    const float* in_w     = (const float*)d_in[1];
    const float* in_b     = (const float*)d_in[2];
    const float* ln1_g    = (const float*)d_in[3];
    const float* ln1_b    = (const float*)d_in[4];
    const float* fc1_w    = (const float*)d_in[5];
    const float* fc1_b    = (const float*)d_in[6];
    const float* ln2_g    = (const float*)d_in[7];
    const float* ln2_b    = (const float*)d_in[8];
    const float* fc2_w    = (const float*)d_in[9];
    const float* fc2_b    = (const float*)d_in[10];
    const float* out_ln_g = (const float*)d_in[11];
    const float* out_ln_b = (const float*)d_in[12];
    const float* out_w    = (const float*)d_in[13];
    const float* out_b    = (const float*)d_in[14];
    float* out = (float*)d_out;
    unsigned short* wpk = (unsigned short*)d_ws;   // needs 20,971,520 B

    (void)hipFuncSetAttribute((const void*)mlp_fused,
                              hipFuncAttributeMaxDynamicSharedMemorySize, SMEM_BYTES);

    pack_weights<<<5120, 256, 0, stream>>>(fc1_w, fc2_w, wpk);
    mlp_fused<<<1024, 1024, SMEM_BYTES, stream>>>(
        x, in_w, in_b, ln1_g, ln1_b, fc1_b, ln2_g, ln2_b, fc2_b,
        out_ln_g, out_ln_b, out_w, out_b, wpk, out);
}

// Round 6
// 1989.986 us; speedup vs baseline: 1.1127x; 1.0444x over previous
//
#include <hip/hip_runtime.h>

// ---------------------------------------------------------------------------
// Fused residual-MLP (N=65536, HID=512, NB=20) for gfx950.  Round 6.
//
// R5 post-mortem: bound by serialized per-phase VALU (LN normalize + f2bf +
// stats), not L2 BW (R5 halved traffic, no gain) nor occupancy (R4 doubled,
// no gain). MfmaUtil 29 / VALUBusy 48 / conflicts 15% ~ sums to runtime.
//
// R6: fold LN affine into the GEMM:
//   LN(h)@W = inv*(h @ (g.W)) - inv*m*u + v,  u = g@W, v = beta@W (+fc bias)
//  - pack kernel scales W rows by gamma; make_uv computes u, v+fc_b (fp32).
//  - GEMM input = raw bf16(h): write_norm's normalize pipeline deleted,
//    replaced by a bare f2bf cast fused into the stats-partial loop.
//  - LN applied in the fp32 epilogue: 2 fma/elem. Residual/bias also in
//    epilogue (acc starts at 0).
//  - stats phase-2 reduce moved BEFORE do_gemm between the same barriers ->
//    overlaps with other waves' MFMA. Barriers 6 -> 4 per block.
// Structure/primitives otherwise R5-proven: 64-row tiles, 16 waves x 32
// cols, hn stride 520, packed-bf16 partial plane stride 67, LDS 135680 B.
// ---------------------------------------------------------------------------

typedef float  fvec4 __attribute__((ext_vector_type(4)));
typedef __bf16 bvec8 __attribute__((ext_vector_type(8)));

#define HN_STRIDE 520                 // ushorts per hn row (proven R1/R4/R5)
#define PL_STRIDE 67                  // u32 per pcol (proven R5)
#define N_PCOL    256
#define WCHUNK    16384               // ushorts per (b,slot,w) weight chunk
#define SMEM_BYTES (64*HN_STRIDE*2 + N_PCOL*PL_STRIDE*4 + 64*8)  // 135680
#define WPK_USHORTS ((size_t)20*2*16*WCHUNK)   // 10,485,760

__device__ __forceinline__ unsigned int f2bf(float v) {
    unsigned int u = __float_as_uint(v);
    return (u + 0x7fffu + ((u >> 16) & 1u)) >> 16;   // RNE to bf16
}
__device__ __forceinline__ float silu_f(float v) {
    return v * (1.0f / (1.0f + __expf(-v)));
}

// ---- weight pre-pack: bf16(gamma_k * W[b][k][n]) in MFMA B-fragment order -
__global__ __launch_bounds__(256) void pack_weights(
        const float* __restrict__ w1, const float* __restrict__ w2,
        const float* __restrict__ g1, const float* __restrict__ g2,
        unsigned short* __restrict__ pk) {
    int tid = blockIdx.x * 256 + threadIdx.x;
    int l  = tid & 63;
    int f  = tid >> 6;
    int t  = f & 1;
    int kc = (f >> 1) & 15;
    int w  = (f >> 5) & 15;
    int g  = (f >> 9) & 1;
    int b  = f >> 10;
    const float* src = g ? w2 : w1;
    const float* gs  = (g ? g2 : g1) + b * 512;
    int k0 = kc * 32 + (l >> 4) * 8;
    int n  = w * 32 + (l & 15) * 2 + t;
    const float* s = src + ((size_t)b * 512 + k0) * 512 + n;
    unsigned int r[4];
#pragma unroll
    for (int j = 0; j < 4; ++j) {
        float ga = gs[k0 + 2 * j];
        float gb = gs[k0 + 2 * j + 1];
        unsigned int lo = f2bf(ga * s[(size_t)(2*j) * 512]);
        unsigned int hi = f2bf(gb * s[(size_t)(2*j + 1) * 512]);
        r[j] = lo | (hi << 16);
    }
    *(uint4*)(pk + (size_t)tid * 8) = make_uint4(r[0], r[1], r[2], r[3]);
}

// ---- u/vc precompute: u_n = sum_j g_j W_jn ; vc_n = sum_j beta_j W_jn + fcb_n
__global__ __launch_bounds__(512) void make_uv(
        const float* __restrict__ w1, const float* __restrict__ w2,
        const float* __restrict__ g1, const float* __restrict__ bl1,
        const float* __restrict__ cb1,
        const float* __restrict__ g2, const float* __restrict__ bl2,
        const float* __restrict__ cb2,
        float* __restrict__ uv) {
    int b = blockIdx.x >> 1, slot = blockIdx.x & 1, n = threadIdx.x;
    const float* W  = (slot ? w2 : w1) + (size_t)b * 512 * 512;
    const float* g  = (slot ? g2 : g1) + b * 512;
    const float* bl = (slot ? bl2 : bl1) + b * 512;
    const float* cb = (slot ? cb2 : cb1) + b * 512;
    float u = 0.f, v = 0.f;
    for (int j = 0; j < 512; ++j) {
        float wv = W[(size_t)j * 512 + n];
        u = fmaf(g[j], wv, u);
        v = fmaf(bl[j], wv, v);
    }
    uv[((b * 2 + slot) * 2 + 0) * 512 + n] = u;
    uv[((b * 2 + slot) * 2 + 1) * 512 + n] = v + cb[n];
}

// ---- phase-2 LN reduce: plane -> mv (all 1024 threads) --------------------
__device__ __forceinline__ void reduce_mv(const unsigned int* plane,
                                          float2* mv, int tid) {
    int r = tid >> 4, j = tid & 15;
    float s = 0.f, ss = 0.f;
#pragma unroll
    for (int u = 0; u < 16; ++u) {
        unsigned int pv = plane[(j + 16 * u) * PL_STRIDE + r];
        s  += __uint_as_float(pv << 16);
        ss += __uint_as_float(pv & 0xFFFF0000u);
    }
    s += __shfl_xor(s, 1); ss += __shfl_xor(ss, 1);
    s += __shfl_xor(s, 2); ss += __shfl_xor(ss, 2);
    s += __shfl_xor(s, 4); ss += __shfl_xor(ss, 4);
    s += __shfl_xor(s, 8); ss += __shfl_xor(ss, 8);
    if (j == 0) {
        float mean = s * (1.f / 512.f);
        float var  = ss * (1.f / 512.f) - mean * mean;
        mv[r] = make_float2(mean, rsqrtf(var + 1e-5f));
    }
}

// ---- one [64,512]x[512,512] GEMM: A from LDS, B streamed from global ------
__device__ __forceinline__ void do_gemm(fvec4 acc[4][2],
                                        const unsigned short* hn,
                                        const unsigned short* __restrict__ wp,
                                        int l, int c, int q) {
#pragma unroll 2
    for (int kc = 0; kc < 16; ++kc) {
        bvec8 a[4], bb[2];
#pragma unroll
        for (int rb = 0; rb < 4; ++rb)
            a[rb] = *(const bvec8*)(hn + (rb * 16 + c) * HN_STRIDE + kc * 32 + q * 8);
#pragma unroll
        for (int t = 0; t < 2; ++t)
            bb[t] = *(const bvec8*)(wp + (kc * 2 + t) * 512 + l * 8);
#pragma unroll
        for (int rb = 0; rb < 4; ++rb)
#pragma unroll
            for (int t = 0; t < 2; ++t)
                acc[rb][t] = __builtin_amdgcn_mfma_f32_16x16x32_bf16(
                    a[rb], bb[t], acc[rb][t], 0, 0, 0);
    }
}

__global__ __launch_bounds__(1024, 4) void mlp_fused(
        const float* __restrict__ x,
        const float* __restrict__ in_w,  const float* __restrict__ in_b,
        const float* __restrict__ out_ln_g, const float* __restrict__ out_ln_b,
        const float* __restrict__ out_w, const float* __restrict__ out_b,
        const unsigned short* __restrict__ wpk,
        const float* __restrict__ uv,
        float* __restrict__ out) {
    extern __shared__ char smem[];
    unsigned short* hn = (unsigned short*)smem;                      // 66560 B
    unsigned int* plane = (unsigned int*)(smem + 64 * HN_STRIDE * 2);// 68608 B
    float* planef = (float*)plane;
    float2* mv = (float2*)(smem + 64 * HN_STRIDE * 2 + N_PCOL * PL_STRIDE * 4);

    const int tid = threadIdx.x;
    const int w = tid >> 6;            // wave 0..15 -> cols [32w, 32w+32)
    const int l = tid & 63, c = l & 15, q = l >> 4;
    const int colbase = w * 32 + c * 2;
    const int pcol = w * 16 + c;       // 0..255
    const int row0 = blockIdx.x * 64;

    float h[4][4][2];   // [rb][i][t] : row rb*16+q*4+i, col colbase+t

    // ---- in-proj + SiLU ----
    {
        float2 iw0 = *(const float2*)(in_w + colbase);
        float2 iw1 = *(const float2*)(in_w + 512 + colbase);
        float2 ib  = *(const float2*)(in_b + colbase);
#pragma unroll
        for (int rb = 0; rb < 4; ++rb)
#pragma unroll
            for (int i = 0; i < 4; ++i) {
                int row = rb * 16 + q * 4 + i;
                float2 xv = *(const float2*)(x + (size_t)(row0 + row) * 2);
                h[rb][i][0] = silu_f(xv.x * iw0.x + xv.y * iw1.x + ib.x);
                h[rb][i][1] = silu_f(xv.x * iw0.y + xv.y * iw1.y + ib.y);
            }
    }

    for (int b = 0; b < 20; ++b) {
        // per-block epilogue constants (L2-hot)
        float2 u1  = *(const float2*)(uv + ((b * 2 + 0) * 2 + 0) * 512 + colbase);
        float2 vc1 = *(const float2*)(uv + ((b * 2 + 0) * 2 + 1) * 512 + colbase);
        float2 u2  = *(const float2*)(uv + ((b * 2 + 1) * 2 + 0) * 512 + colbase);
        float2 vc2 = *(const float2*)(uv + ((b * 2 + 1) * 2 + 1) * 512 + colbase);

        // phase A: stats1 partials + hn = bf16(h)   (raw cast, no normalize)
#pragma unroll
        for (int rb = 0; rb < 4; ++rb)
#pragma unroll
            for (int i = 0; i < 4; ++i) {
                int row = rb * 16 + q * 4 + i;
                float v0 = h[rb][i][0], v1 = h[rb][i][1];
                plane[pcol * PL_STRIDE + row] =
                    f2bf(v0 + v1) | (f2bf(__builtin_fmaf(v0, v0, v1 * v1)) << 16);
                *(unsigned int*)(hn + row * HN_STRIDE + colbase) =
                    f2bf(v0) | (f2bf(v1) << 16);
            }
        __syncthreads();                               // bar1
        reduce_mv(plane, mv, tid);                     // overlaps gemm1 (other waves)

        fvec4 acc[4][2];
#pragma unroll
        for (int rb = 0; rb < 4; ++rb)
#pragma unroll
            for (int t = 0; t < 2; ++t) acc[rb][t] = (fvec4){0.f, 0.f, 0.f, 0.f};
        do_gemm(acc, hn, wpk + ((size_t)(b * 2 + 0) * 16 + w) * WCHUNK, l, c, q);
        __syncthreads();                               // bar2

        // epilogue1: t = silu(inv*acc - inv*m*u1 + vc1); fused stats2 + cast
#pragma unroll
        for (int rb = 0; rb < 4; ++rb)
#pragma unroll
            for (int i = 0; i < 4; ++i) {
                int row = rb * 16 + q * 4 + i;
                float2 m = mv[row];
                float minv = -m.x * m.y;
                float t0 = silu_f(__builtin_fmaf(acc[rb][0][i], m.y,
                                  __builtin_fmaf(minv, u1.x, vc1.x)));
                float t1 = silu_f(__builtin_fmaf(acc[rb][1][i], m.y,
                                  __builtin_fmaf(minv, u1.y, vc1.y)));
                plane[pcol * PL_STRIDE + row] =
                    f2bf(t0 + t1) | (f2bf(__builtin_fmaf(t0, t0, t1 * t1)) << 16);
                *(unsigned int*)(hn + row * HN_STRIDE + colbase) =
                    f2bf(t0) | (f2bf(t1) << 16);
            }
        __syncthreads();                               // bar3
        reduce_mv(plane, mv, tid);                     // overlaps gemm2

#pragma unroll
        for (int rb = 0; rb < 4; ++rb)
#pragma unroll
            for (int t = 0; t < 2; ++t) acc[rb][t] = (fvec4){0.f, 0.f, 0.f, 0.f};
        do_gemm(acc, hn, wpk + ((size_t)(b * 2 + 1) * 16 + w) * WCHUNK, l, c, q);
        __syncthreads();                               // bar4

        // epilogue2: h += inv*acc - inv*m*u2 + vc2   (residual in fp32)
#pragma unroll
        for (int rb = 0; rb < 4; ++rb)
#pragma unroll
            for (int i = 0; i < 4; ++i) {
                int row = rb * 16 + q * 4 + i;
                float2 m = mv[row];
                float minv = -m.x * m.y;
                h[rb][i][0] = __builtin_fmaf(acc[rb][0][i], m.y,
                    h[rb][i][0] + __builtin_fmaf(minv, u2.x, vc2.x));
                h[rb][i][1] = __builtin_fmaf(acc[rb][1][i], m.y,
                    h[rb][i][1] + __builtin_fmaf(minv, u2.y, vc2.y));
            }
    }

    // ---- final LN + SiLU + out-proj (classic path, once) ----
#pragma unroll
    for (int rb = 0; rb < 4; ++rb)
#pragma unroll
        for (int i = 0; i < 4; ++i) {
            int row = rb * 16 + q * 4 + i;
            float v0 = h[rb][i][0], v1 = h[rb][i][1];
            plane[pcol * PL_STRIDE + row] =
                f2bf(v0 + v1) | (f2bf(__builtin_fmaf(v0, v0, v1 * v1)) << 16);
        }
    __syncthreads();
    reduce_mv(plane, mv, tid);
    __syncthreads();
    {
        float2 og = *(const float2*)(out_ln_g + colbase);
        float2 ob = *(const float2*)(out_ln_b + colbase);
        float2 ow = *(const float2*)(out_w + colbase);
#pragma unroll
        for (int rb = 0; rb < 4; ++rb)
#pragma unroll
            for (int i = 0; i < 4; ++i) {
                int row = rb * 16 + q * 4 + i;
                float2 m = mv[row];
                float v0 = (h[rb][i][0] - m.x) * m.y * og.x + ob.x;
                float v1 = (h[rb][i][1] - m.x) * m.y * og.y + ob.y;
                planef[pcol * PL_STRIDE + row] = silu_f(v0) * ow.x + silu_f(v1) * ow.y;
            }
    }
    __syncthreads();
    {
        int r = tid >> 4, j = tid & 15;
        float s = 0.f;
#pragma unroll
        for (int u = 0; u < 16; ++u)
            s += planef[(j + 16 * u) * PL_STRIDE + r];
        s += __shfl_xor(s, 1);
        s += __shfl_xor(s, 2);
        s += __shfl_xor(s, 4);
        s += __shfl_xor(s, 8);
        if (j == 0) out[row0 + r] = s + out_b[0];
    }
}

extern "C" void kernel_launch(void* const* d_in, const int* in_sizes, int n_in,
                              void* d_out, int out_size, void* d_ws, size_t ws_size,
                              hipStream_t stream) {
    const float* x        = (const float*)d_in[0];
    const float* in_w     = (const float*)d_in[1];
    const float* in_b     = (const float*)d_in[2];
    const float* ln1_g    = (const float*)d_in[3];
    const float* ln1_b    = (const float*)d_in[4];
    const float* fc1_w    = (const float*)d_in[5];
    const float* fc1_b    = (const float*)d_in[6];
    const float* ln2_g    = (const float*)d_in[7];
    const float* ln2_b    = (const float*)d_in[8];
    const float* fc2_w    = (const float*)d_in[9];
    const float* fc2_b    = (const float*)d_in[10];
    const float* out_ln_g = (const float*)d_in[11];
    const float* out_ln_b = (const float*)d_in[12];
    const float* out_w    = (const float*)d_in[13];
    const float* out_b    = (const float*)d_in[14];
    float* out = (float*)d_out;
    unsigned short* wpk = (unsigned short*)d_ws;            // 20,971,520 B
    float* uv = (float*)((char*)d_ws + WPK_USHORTS * 2);    //    163,840 B

    (void)hipFuncSetAttribute((const void*)mlp_fused,
                              hipFuncAttributeMaxDynamicSharedMemorySize, SMEM_BYTES);

    pack_weights<<<5120, 256, 0, stream>>>(fc1_w, fc2_w, ln1_g, ln2_g, wpk);
    make_uv<<<40, 512, 0, stream>>>(fc1_w, fc2_w, ln1_g, ln1_b, fc1_b,
                                    ln2_g, ln2_b, fc2_b, uv);
    mlp_fused<<<1024, 1024, SMEM_BYTES, stream>>>(
        x, in_w, in_b, out_ln_g, out_ln_b, out_w, out_b, wpk, uv, out);
}

// Round 8
// 1776.180 us; speedup vs baseline: 1.2466x; 1.1204x over previous
//
#include <hip/hip_runtime.h>
#include <hip/hip_bf16.h>

// ---------------------------------------------------------------------------
// Fused residual-MLP (N=65536, HID=512, NB=20) for gfx950.  Round 8.
// (R7 retry: fix '__builtin_bit_cast source not trivially copyable' on
//  __hip_bfloat162 by using __builtin_memcpy. No other changes.)
//
// R6 post-mortem: GEMM phase oversubscribed on A-LDS (8.2k cyc/GEMM vs 5k
// MFMA) and B-L2 stream (2.9e6 cyc/CU = 60% of timeline); phases serialize
// at barriers. R7/R8 = overlap + trim, same proven 64-row/16-wave geometry:
//  - plane DELETED: LN stats read straight from hn (bf16), reduce
//    INTERLEAVED into the GEMM kc-loop (hidden under MFMA; mv ready at the
//    barrier the epilogue already crosses). LDS 135.7 -> 67 KB.
//  - packed casts: __float22bfloat162_rn (v_cvt_pk_bf16_f32, RNE).
//  - B-prefetch: kc=0 B-frags of each GEMM loaded during the preceding
//    epilogue phase, carried across the barrier in VGPRs.
// Barriers stay 4/block. All LDS patterns bank-audited (A-read + stats-read
// both land 8 dwords/bank = data-volume minimum).
// ---------------------------------------------------------------------------

typedef float  fvec4 __attribute__((ext_vector_type(4)));
typedef __bf16 bvec8 __attribute__((ext_vector_type(8)));

#define HN_STRIDE 520                 // ushorts per hn row (proven R1/R4-R6)
#define WCHUNK    16384               // ushorts per (b,slot,w) weight chunk
#define SMEM_BYTES (64*HN_STRIDE*2 + 64*8)       // 66560 + 512 = 67072
#define WPK_USHORTS ((size_t)20*2*16*WCHUNK)     // 10,485,760

__device__ __forceinline__ unsigned int f2bf(float v) {
    unsigned int u = __float_as_uint(v);
    return (u + 0x7fffu + ((u >> 16) & 1u)) >> 16;   // RNE to bf16
}
__device__ __forceinline__ unsigned int pkbf(float a, float b) {
    __hip_bfloat162 t = __float22bfloat162_rn(make_float2(a, b));
    unsigned int r;
    __builtin_memcpy(&r, &t, 4);                     // v_cvt_pk_bf16_f32
    return r;
}
__device__ __forceinline__ float silu_f(float v) {
    return v * (1.0f / (1.0f + __expf(-v)));
}

// ---- weight pre-pack: bf16(gamma_k * W[b][k][n]) in MFMA B-fragment order -
__global__ __launch_bounds__(256) void pack_weights(
        const float* __restrict__ w1, const float* __restrict__ w2,
        const float* __restrict__ g1, const float* __restrict__ g2,
        unsigned short* __restrict__ pk) {
    int tid = blockIdx.x * 256 + threadIdx.x;
    int l  = tid & 63;
    int f  = tid >> 6;
    int t  = f & 1;
    int kc = (f >> 1) & 15;
    int w  = (f >> 5) & 15;
    int g  = (f >> 9) & 1;
    int b  = f >> 10;
    const float* src = g ? w2 : w1;
    const float* gs  = (g ? g2 : g1) + b * 512;
    int k0 = kc * 32 + (l >> 4) * 8;
    int n  = w * 32 + (l & 15) * 2 + t;
    const float* s = src + ((size_t)b * 512 + k0) * 512 + n;
    unsigned int r[4];
#pragma unroll
    for (int j = 0; j < 4; ++j) {
        float ga = gs[k0 + 2 * j];
        float gb = gs[k0 + 2 * j + 1];
        unsigned int lo = f2bf(ga * s[(size_t)(2*j) * 512]);
        unsigned int hi = f2bf(gb * s[(size_t)(2*j + 1) * 512]);
        r[j] = lo | (hi << 16);
    }
    *(uint4*)(pk + (size_t)tid * 8) = make_uint4(r[0], r[1], r[2], r[3]);
}

// ---- u/vc precompute: u_n = sum_j g_j W_jn ; vc_n = sum_j beta_j W_jn + fcb_n
__global__ __launch_bounds__(512) void make_uv(
        const float* __restrict__ w1, const float* __restrict__ w2,
        const float* __restrict__ g1, const float* __restrict__ bl1,
        const float* __restrict__ cb1,
        const float* __restrict__ g2, const float* __restrict__ bl2,
        const float* __restrict__ cb2,
        float* __restrict__ uv) {
    int b = blockIdx.x >> 1, slot = blockIdx.x & 1, n = threadIdx.x;
    const float* W  = (slot ? w2 : w1) + (size_t)b * 512 * 512;
    const float* g  = (slot ? g2 : g1) + b * 512;
    const float* bl = (slot ? bl2 : bl1) + b * 512;
    const float* cb = (slot ? cb2 : cb1) + b * 512;
    float u = 0.f, v = 0.f;
    for (int j = 0; j < 512; ++j) {
        float wv = W[(size_t)j * 512 + n];
        u = fmaf(g[j], wv, u);
        v = fmaf(bl[j], wv, v);
    }
    uv[((b * 2 + slot) * 2 + 0) * 512 + n] = u;
    uv[((b * 2 + slot) * 2 + 1) * 512 + n] = v + cb[n];
}

__device__ __forceinline__ void acc_u32(unsigned int u, float& s, float& ss) {
    float lo = __uint_as_float(u << 16);
    float hi = __uint_as_float(u & 0xFFFF0000u);
    s += lo + hi;
    ss = __builtin_fmaf(lo, lo, ss);
    ss = __builtin_fmaf(hi, hi, ss);
}

// ---- GEMM with LN-stats reduce interleaved into the kc loop ---------------
// Stats of the CURRENT hn contents land in mv (visible after next barrier).
__device__ __forceinline__ void gemm_red(
        fvec4 acc[4][2], const unsigned short* hn,
        const unsigned short* __restrict__ wp, uint4 pre0, uint4 pre1,
        float2* mv, int l, int c, int q, int tid) {
    const uint4* wp4 = (const uint4*)wp;
    const int r = tid >> 4, j = tid & 15;
    float s = 0.f, ss = 0.f;
#pragma unroll
    for (int kc = 0; kc < 16; ++kc) {
        bvec8 a[4], b0, b1;
#pragma unroll
        for (int rb = 0; rb < 4; ++rb)
            a[rb] = *(const bvec8*)(hn + (rb * 16 + c) * HN_STRIDE + kc * 32 + q * 8);
        if (kc == 0) {
            __builtin_memcpy(&b0, &pre0, 16);
            __builtin_memcpy(&b1, &pre1, 16);
        } else {
            uint4 r0 = wp4[(kc * 2 + 0) * 64 + l];
            uint4 r1 = wp4[(kc * 2 + 1) * 64 + l];
            __builtin_memcpy(&b0, &r0, 16);
            __builtin_memcpy(&b1, &r1, 16);
        }
        if (kc >= 4 && kc < 8) {   // 4 stats chunks hidden under the MFMA stream
            uint4 pv = *(const uint4*)(hn + r * HN_STRIDE + (j + 16 * (kc - 4)) * 8);
            acc_u32(pv.x, s, ss); acc_u32(pv.y, s, ss);
            acc_u32(pv.z, s, ss); acc_u32(pv.w, s, ss);
        }
#pragma unroll
        for (int rb = 0; rb < 4; ++rb) {
            acc[rb][0] = __builtin_amdgcn_mfma_f32_16x16x32_bf16(a[rb], b0, acc[rb][0], 0, 0, 0);
            acc[rb][1] = __builtin_amdgcn_mfma_f32_16x16x32_bf16(a[rb], b1, acc[rb][1], 0, 0, 0);
        }
    }
    s += __shfl_xor(s, 1); ss += __shfl_xor(ss, 1);
    s += __shfl_xor(s, 2); ss += __shfl_xor(ss, 2);
    s += __shfl_xor(s, 4); ss += __shfl_xor(ss, 4);
    s += __shfl_xor(s, 8); ss += __shfl_xor(ss, 8);
    if (j == 0) {
        float mean = s * (1.f / 512.f);
        float var  = ss * (1.f / 512.f) - mean * mean;
        mv[r] = make_float2(mean, rsqrtf(var + 1e-5f));
    }
}

// ---- standalone stats from hn (final LN) ----------------------------------
__device__ __forceinline__ void reduce_mv_hn(const unsigned short* hn,
                                             float2* mv, int tid) {
    int r = tid >> 4, j = tid & 15;
    float s = 0.f, ss = 0.f;
#pragma unroll
    for (int u = 0; u < 4; ++u) {
        uint4 pv = *(const uint4*)(hn + r * HN_STRIDE + (j + 16 * u) * 8);
        acc_u32(pv.x, s, ss); acc_u32(pv.y, s, ss);
        acc_u32(pv.z, s, ss); acc_u32(pv.w, s, ss);
    }
    s += __shfl_xor(s, 1); ss += __shfl_xor(ss, 1);
    s += __shfl_xor(s, 2); ss += __shfl_xor(ss, 2);
    s += __shfl_xor(s, 4); ss += __shfl_xor(ss, 4);
    s += __shfl_xor(s, 8); ss += __shfl_xor(ss, 8);
    if (j == 0) {
        float mean = s * (1.f / 512.f);
        float var  = ss * (1.f / 512.f) - mean * mean;
        mv[r] = make_float2(mean, rsqrtf(var + 1e-5f));
    }
}

__global__ __launch_bounds__(1024, 4) void mlp_fused(
        const float* __restrict__ x,
        const float* __restrict__ in_w,  const float* __restrict__ in_b,
        const float* __restrict__ out_ln_g, const float* __restrict__ out_ln_b,
        const float* __restrict__ out_w, const float* __restrict__ out_b,
        const unsigned short* __restrict__ wpk,
        const float* __restrict__ uv,
        float* __restrict__ out) {
    extern __shared__ char smem[];
    unsigned short* hn = (unsigned short*)smem;                  // 66560 B
    float* hnf = (float*)smem;                                   // alias (final)
    float2* mv = (float2*)(smem + 64 * HN_STRIDE * 2);           //   512 B

    const int tid = threadIdx.x;
    const int w = tid >> 6;            // wave 0..15 -> cols [32w, 32w+32)
    const int l = tid & 63, c = l & 15, q = l >> 4;
    const int colbase = w * 32 + c * 2;
    const int row0 = blockIdx.x * 64;

    float h[4][4][2];   // [rb][i][t] : row rb*16+q*4+i, col colbase+t

    // ---- in-proj + SiLU ----
    {
        float2 iw0 = *(const float2*)(in_w + colbase);
        float2 iw1 = *(const float2*)(in_w + 512 + colbase);
        float2 ib  = *(const float2*)(in_b + colbase);
#pragma unroll
        for (int rb = 0; rb < 4; ++rb)
#pragma unroll
            for (int i = 0; i < 4; ++i) {
                int row = rb * 16 + q * 4 + i;
                float2 xv = *(const float2*)(x + (size_t)(row0 + row) * 2);
                h[rb][i][0] = silu_f(xv.x * iw0.x + xv.y * iw1.x + ib.x);
                h[rb][i][1] = silu_f(xv.x * iw0.y + xv.y * iw1.y + ib.y);
            }
    }

    for (int b = 0; b < 20; ++b) {
        const unsigned short* wp1 = wpk + ((size_t)(b * 2 + 0) * 16 + w) * WCHUNK;
        const unsigned short* wp2 = wpk + ((size_t)(b * 2 + 1) * 16 + w) * WCHUNK;
        float2 u1  = *(const float2*)(uv + ((b * 2 + 0) * 2 + 0) * 512 + colbase);
        float2 vc1 = *(const float2*)(uv + ((b * 2 + 0) * 2 + 1) * 512 + colbase);
        float2 u2  = *(const float2*)(uv + ((b * 2 + 1) * 2 + 0) * 512 + colbase);
        float2 vc2 = *(const float2*)(uv + ((b * 2 + 1) * 2 + 1) * 512 + colbase);

        // phase A: hn = bf16(h) (packed cast) + prefetch gemm1 kc=0 B-frags
        uint4 pre0 = ((const uint4*)wp1)[l];
        uint4 pre1 = ((const uint4*)wp1)[64 + l];
#pragma unroll
        for (int rb = 0; rb < 4; ++rb)
#pragma unroll
            for (int i = 0; i < 4; ++i) {
                int row = rb * 16 + q * 4 + i;
                *(unsigned int*)(hn + row * HN_STRIDE + colbase) =
                    pkbf(h[rb][i][0], h[rb][i][1]);
            }
        __syncthreads();                               // bar1

        fvec4 acc[4][2];
#pragma unroll
        for (int rb = 0; rb < 4; ++rb)
#pragma unroll
            for (int t = 0; t < 2; ++t) acc[rb][t] = (fvec4){0.f, 0.f, 0.f, 0.f};
        gemm_red(acc, hn, wp1, pre0, pre1, mv, l, c, q, tid);
        __syncthreads();                               // bar2 (mv1 + hn reads done)

        // epilogue1: t = silu(inv*acc - inv*m*u1 + vc1) -> hn ; prefetch gemm2
        pre0 = ((const uint4*)wp2)[l];
        pre1 = ((const uint4*)wp2)[64 + l];
#pragma unroll
        for (int rb = 0; rb < 4; ++rb)
#pragma unroll
            for (int i = 0; i < 4; ++i) {
                int row = rb * 16 + q * 4 + i;
                float2 m = mv[row];
                float minv = -m.x * m.y;
                float t0 = silu_f(__builtin_fmaf(acc[rb][0][i], m.y,
                                  __builtin_fmaf(minv, u1.x, vc1.x)));
                float t1 = silu_f(__builtin_fmaf(acc[rb][1][i], m.y,
                                  __builtin_fmaf(minv, u1.y, vc1.y)));
                *(unsigned int*)(hn + row * HN_STRIDE + colbase) = pkbf(t0, t1);
            }
        __syncthreads();                               // bar3

#pragma unroll
        for (int rb = 0; rb < 4; ++rb)
#pragma unroll
            for (int t = 0; t < 2; ++t) acc[rb][t] = (fvec4){0.f, 0.f, 0.f, 0.f};
        gemm_red(acc, hn, wp2, pre0, pre1, mv, l, c, q, tid);
        __syncthreads();                               // bar4 (mv2 + hn reads done)

        // epilogue2: h += inv*acc - inv*m*u2 + vc2   (residual in fp32)
#pragma unroll
        for (int rb = 0; rb < 4; ++rb)
#pragma unroll
            for (int i = 0; i < 4; ++i) {
                int row = rb * 16 + q * 4 + i;
                float2 m = mv[row];
                float minv = -m.x * m.y;
                h[rb][i][0] = __builtin_fmaf(acc[rb][0][i], m.y,
                    h[rb][i][0] + __builtin_fmaf(minv, u2.x, vc2.x));
                h[rb][i][1] = __builtin_fmaf(acc[rb][1][i], m.y,
                    h[rb][i][1] + __builtin_fmaf(minv, u2.y, vc2.y));
            }
    }

    // ---- final LN + SiLU + out-proj ----
#pragma unroll
    for (int rb = 0; rb < 4; ++rb)
#pragma unroll
        for (int i = 0; i < 4; ++i) {
            int row = rb * 16 + q * 4 + i;
            *(unsigned int*)(hn + row * HN_STRIDE + colbase) =
                pkbf(h[rb][i][0], h[rb][i][1]);
        }
    __syncthreads();
    reduce_mv_hn(hn, mv, tid);
    __syncthreads();
    {
        float2 og = *(const float2*)(out_ln_g + colbase);
        float2 ob = *(const float2*)(out_ln_b + colbase);
        float2 ow = *(const float2*)(out_w + colbase);
        const int pcol = w * 16 + c;
#pragma unroll
    for (int rb = 0; rb < 4; ++rb)
#pragma unroll
            for (int i = 0; i < 4; ++i) {
                int row = rb * 16 + q * 4 + i;
                float2 m = mv[row];
                float v0 = (h[rb][i][0] - m.x) * m.y * og.x + ob.x;
                float v1 = (h[rb][i][1] - m.x) * m.y * og.y + ob.y;
                hnf[pcol * 65 + row] = silu_f(v0) * ow.x + silu_f(v1) * ow.y;
            }
    }
    __syncthreads();
    {
        int r = tid >> 4, j = tid & 15;
        float s = 0.f;
#pragma unroll
        for (int u = 0; u < 16; ++u)
            s += hnf[(j + 16 * u) * 65 + r];
        s += __shfl_xor(s, 1);
        s += __shfl_xor(s, 2);
        s += __shfl_xor(s, 4);
        s += __shfl_xor(s, 8);
        if (j == 0) out[row0 + r] = s + out_b[0];
    }
}

extern "C" void kernel_launch(void* const* d_in, const int* in_sizes, int n_in,
                              void* d_out, int out_size, void* d_ws, size_t ws_size,
                              hipStream_t stream) {
    const float* x        = (const float*)d_in[0];
    const float* in_w     = (const float*)d_in[1];
    const float* in_b     = (const float*)d_in[2];
    const float* ln1_g    = (const float*)d_in[3];
    const float* ln1_b    = (const float*)d_in[4];
    const float* fc1_w    = (const float*)d_in[5];
    const float* fc1_b    = (const float*)d_in[6];
    const float* ln2_g    = (const float*)d_in[7];
    const float* ln2_b    = (const float*)d_in[8];
    const float* fc2_w    = (const float*)d_in[9];
    const float* fc2_b    = (const float*)d_in[10];
    const float* out_ln_g = (const float*)d_in[11];
    const float* out_ln_b = (const float*)d_in[12];
    const float* out_w    = (const float*)d_in[13];
    const float* out_b    = (const float*)d_in[14];
    float* out = (float*)d_out;
    unsigned short* wpk = (unsigned short*)d_ws;            // 20,971,520 B
    float* uv = (float*)((char*)d_ws + WPK_USHORTS * 2);    //    163,840 B

    (void)hipFuncSetAttribute((const void*)mlp_fused,
                              hipFuncAttributeMaxDynamicSharedMemorySize, SMEM_BYTES);

    pack_weights<<<5120, 256, 0, stream>>>(fc1_w, fc2_w, ln1_g, ln2_g, wpk);
    make_uv<<<40, 512, 0, stream>>>(fc1_w, fc2_w, ln1_g, ln1_b, fc1_b,
                                    ln2_g, ln2_b, fc2_b, uv);
    mlp_fused<<<1024, 1024, SMEM_BYTES, stream>>>(
        x, in_w, in_b, out_ln_g, out_ln_b, out_w, out_b, wpk, uv, out);
}